// Round 1
// baseline (1026.893 us; speedup 1.0000x reference)
//
#include <hip/hip_runtime.h>
#include <hip/hip_bf16.h>

#define B_SZ 8192
#define KNB 16
#define BK 131072
#define ED 256

typedef __attribute__((ext_vector_type(8))) short short8v;
typedef __attribute__((ext_vector_type(4))) float floatx4;

static __device__ __forceinline__ unsigned short f2bf(float f) {
  unsigned int u = __float_as_uint(f);
  u = (u + 0x7FFFu + ((u >> 16) & 1u)) >> 16;
  return (unsigned short)u;
}
static __device__ __forceinline__ float bf2f(unsigned short u) {
  return __uint_as_float(((unsigned int)u) << 16);
}
static __device__ __forceinline__ float gelu_erf(float x) {
  return 0.5f * x * (1.0f + erff(x * 0.70710678118654752f));
}
// gelu via odd Taylor of erf(x/sqrt(2)); exact to ~1e-9 for |x|<0.5 (FF2/FF3 have |x|<0.15)
static __device__ __forceinline__ float gelu_poly(float x) {
  float t = x * x;
  float p = fmaf(t, fmaf(t, fmaf(t, fmaf(t, 2.8935185185e-4f, -2.9761904762e-3f),
                                 2.5e-2f), -1.6666666667e-1f), 1.0f);
  return 0.5f * x * fmaf(0.79788456080286536f * x, p, 1.0f);
}

#define MFMA(a, b, c) __builtin_amdgcn_mfma_f32_16x16x32_bf16((a), (b), (c), 0, 0, 0)

// async global->LDS, 16B per lane, dest = wave-uniform base + lane*16
static __device__ __forceinline__ void gll16(const void* g, void* l) {
  __builtin_amdgcn_global_load_lds(
      (const __attribute__((address_space(1))) unsigned int*)g,
      (__attribute__((address_space(3))) unsigned int*)l, 16, 0, 0);
}

// ---------------- prep: W[K][N] f32 -> WT[N][K] bf16 ----------------
__global__ void wt_kernel(const float* __restrict__ W, unsigned short* __restrict__ WT,
                          int K, int N) {
  int idx = blockIdx.x * 256 + threadIdx.x;
  if (idx >= K * N) return;
  int n = idx / K, k = idx - n * K;
  WT[idx] = f2bf(W[(size_t)k * N + n]);
}

// ---------------- K1: FF1 (gathered input) -> E (bf16), M (bf16) ----------------
__global__ __launch_bounds__(256) void k1_kernel(
    const float* __restrict__ self_obs, const float* __restrict__ obs,
    const unsigned short* __restrict__ We1T, const float* __restrict__ be1,
    const unsigned short* __restrict__ We2T, const float* __restrict__ be2,
    unsigned short* __restrict__ E, unsigned short* __restrict__ M) {
  __shared__ unsigned short Xt[64][136];   // 64 x 128 bf16, +8 pad
  __shared__ unsigned short Ht[64][136];   // 64 x 128 bf16 hidden chunk
  const int tid = threadIdx.x;
  const int wave = tid >> 6, lane = tid & 63, g = lane >> 4, r = lane & 15;
  const int row0 = blockIdx.x * 64;

  // stage gathered X tile, f32 -> bf16
#pragma unroll
  for (int p = 0; p < 8; ++p) {
    int e4 = (p * 256 + tid) * 4;
    int i = e4 >> 7, c = e4 & 127;
    int gi = row0 + i;
    const float* src;
    if (c < 64) src = self_obs + (size_t)(gi & (B_SZ - 1)) * 64 + c;
    else        src = obs + (size_t)(gi >> 4) * 1088 + 64 + (gi & 15) * 64 + (c - 64);
    float4 v = *(const float4*)src;
    ushort4 w;
    w.x = f2bf(v.x); w.y = f2bf(v.y); w.z = f2bf(v.z); w.w = f2bf(v.w);
    *(ushort4*)&Xt[i][c] = w;
  }
  __syncthreads();

  floatx4 eacc[4][4];  // [rt][ct]
#pragma unroll
  for (int a = 0; a < 4; ++a)
#pragma unroll
    for (int c2 = 0; c2 < 4; ++c2) eacc[a][c2] = (floatx4)0.0f;

  for (int chunk = 0; chunk < 4; ++chunk) {
    const int hbase = chunk * 128;
    floatx4 hacc[2][4];  // [ctl][rt]
#pragma unroll
    for (int a = 0; a < 2; ++a)
#pragma unroll
      for (int c2 = 0; c2 < 4; ++c2) hacc[a][c2] = (floatx4)0.0f;

#pragma unroll
    for (int kk = 0; kk < 4; ++kk) {   // K = 128
      short8v afr[4];
#pragma unroll
      for (int rt = 0; rt < 4; ++rt)
        afr[rt] = *(const short8v*)&Xt[rt * 16 + r][kk * 32 + g * 8];
#pragma unroll
      for (int ctl = 0; ctl < 2; ++ctl) {
        int col = hbase + wave * 32 + ctl * 16 + r;
        short8v bfr = *(const short8v*)&We1T[(size_t)col * 128 + kk * 32 + g * 8];
#pragma unroll
        for (int rt = 0; rt < 4; ++rt) hacc[ctl][rt] = MFMA(afr[rt], bfr, hacc[ctl][rt]);
      }
    }
    // bias + gelu(erf) -> Ht
#pragma unroll
    for (int ctl = 0; ctl < 2; ++ctl) {
      int col = hbase + wave * 32 + ctl * 16 + r;
      float bias = be1[col];
#pragma unroll
      for (int rt = 0; rt < 4; ++rt)
#pragma unroll
        for (int q = 0; q < 4; ++q) {
          float h = gelu_erf(hacc[ctl][rt][q] + bias);
          Ht[rt * 16 + g * 4 + q][wave * 32 + ctl * 16 + r] = f2bf(h);
        }
    }
    __syncthreads();
    // layer2 partial: E += gelu(H) @ We2[hbase:hbase+128, :]
#pragma unroll
    for (int kk = 0; kk < 4; ++kk) {
      short8v afr[4];
#pragma unroll
      for (int rt = 0; rt < 4; ++rt)
        afr[rt] = *(const short8v*)&Ht[rt * 16 + r][kk * 32 + g * 8];
#pragma unroll
      for (int ct = 0; ct < 4; ++ct) {
        int col = wave * 64 + ct * 16 + r;
        short8v bfr = *(const short8v*)&We2T[(size_t)col * 512 + hbase + kk * 32 + g * 8];
#pragma unroll
        for (int rt = 0; rt < 4; ++rt) eacc[rt][ct] = MFMA(afr[rt], bfr, eacc[rt][ct]);
      }
    }
    __syncthreads();
  }

  // epilogue: +bias, store E (bf16), 16-row group mean -> M
#pragma unroll
  for (int ct = 0; ct < 4; ++ct) {
    int col = wave * 64 + ct * 16 + r;
    float bias = be2[col];
#pragma unroll
    for (int rt = 0; rt < 4; ++rt) {
      float msum = 0.f;
#pragma unroll
      for (int q = 0; q < 4; ++q) {
        float e = eacc[rt][ct][q] + bias;
        int row = rt * 16 + g * 4 + q;
        E[(size_t)(row0 + row) * ED + col] = f2bf(e);
        msum += e;
      }
      msum += __shfl_xor(msum, 16);
      msum += __shfl_xor(msum, 32);
      if (g == 0) {
        int b = (row0 >> 4) + rt;
        M[(size_t)b * ED + col] = f2bf(msum * 0.0625f);
      }
    }
  }
}

// ---------------- K3: attention logits, operand-swapped streaming design ----------------
// Block: 128 E-rows (b-dim) x 64 Wa1-cols; 4 waves, wave = 64 cols x 32 rows.
// MFMA operand swap: A = Wa1 columns (M-dim, static -> LDS 32 KB, staged once per half),
//                    B = E rows (N-dim, streamed per-lane global->reg, L2/LLC-hot).
// Consequences: (1) col-reduction (dot with Wa2) is in-register + 2 shfls (was 64 shfls);
// (2) NO barriers in the main loop (LDS is read-only after prologue) -> compiler emits
// counted vmcnt waits around the 1-step rotating E prefetch; (3) LDS 32 KB + VGPR<=128
// -> 4 blocks/CU (4 waves/SIMD) vs previous 1 block/CU (2 waves/SIMD).
__global__ __launch_bounds__(256, 4) void k3_fused(
    const unsigned short* __restrict__ E, const unsigned short* __restrict__ M,
    const unsigned short* __restrict__ Wa1T, const float* __restrict__ ba1,
    const float* __restrict__ Wa2, float* __restrict__ PT) {
  __shared__ char Bq[32768];   // 4 kq x [64 cols][128 B], col-XOR swizzled
  const int tid = threadIdx.x;
  const int wave = tid >> 6, lane = tid & 63, g = lane >> 4, r = lane & 15;
  const int bid = blockIdx.x;
  const int xcd = bid & 7, j = bid >> 3;
  const int bs_local = j >> 5, nb = j & 31;     // 32 nb-siblings adjacent -> same XCD
  const int b_slab = xcd * 8 + bs_local;        // 0..63 (slab of 128 b-rows)
  const int col0 = nb * 64;
  const int xsw = (r & 7) << 4;

  // ---- prologue 1: stage Bq <- Wa1_bot (k rows 256..511 => byte +512 per col) ----
#pragma unroll
  for (int kq = 0; kq < 4; ++kq)
#pragma unroll
    for (int rnd = 0; rnd < 2; ++rnd) {
      const int crr = rnd * 32 + wave * 8 + (lane >> 3);
      const char* src = (const char*)Wa1T + (size_t)(col0 + crr) * 1024 + 512
                        + kq * 128 + (((lane & 7) * 16) ^ ((crr & 7) << 4));
      gll16(src, Bq + kq * 8192 + (rnd * 32 + wave * 8) * 128);
    }
  __syncthreads();

  // ---- MV tile in regs: mv[ct][nt] = Wa1_bot_cols x M_rows (M streamed per-lane) ----
  floatx4 mv[4][2];
#pragma unroll
  for (int ct = 0; ct < 4; ++ct) {
    mv[ct][0] = (floatx4)0.0f;
    mv[ct][1] = (floatx4)0.0f;
  }
  {
    const unsigned short* mb0 =
        M + (size_t)(b_slab * 128 + wave * 32 + r) * 256 + g * 8;
    const unsigned short* mb1 = mb0 + 16 * 256;
#pragma unroll
    for (int kq = 0; kq < 4; ++kq)
#pragma unroll
      for (int kk = 0; kk < 2; ++kk) {
        const int off = (kk * 64 + g * 16) ^ xsw;
        const char* ab = Bq + kq * 8192 + r * 128 + off;
        short8v a0 = *(const short8v*)(ab);
        short8v a1 = *(const short8v*)(ab + 2048);
        short8v a2 = *(const short8v*)(ab + 4096);
        short8v a3 = *(const short8v*)(ab + 6144);
        short8v m0 = *(const short8v*)(mb0 + kq * 64 + kk * 32);
        short8v m1 = *(const short8v*)(mb1 + kq * 64 + kk * 32);
        mv[0][0] = MFMA(a0, m0, mv[0][0]); mv[0][1] = MFMA(a0, m1, mv[0][1]);
        mv[1][0] = MFMA(a1, m0, mv[1][0]); mv[1][1] = MFMA(a1, m1, mv[1][1]);
        mv[2][0] = MFMA(a2, m0, mv[2][0]); mv[2][1] = MFMA(a2, m1, mv[2][1]);
        mv[3][0] = MFMA(a3, m0, mv[3][0]); mv[3][1] = MFMA(a3, m1, mv[3][1]);
      }
  }
  __syncthreads();   // all MV reads of Bq(bot) done before restage

  // ---- prologue 2: restage Bq <- Wa1_top; fold ba1 into mv while loads fly ----
#pragma unroll
  for (int kq = 0; kq < 4; ++kq)
#pragma unroll
    for (int rnd = 0; rnd < 2; ++rnd) {
      const int crr = rnd * 32 + wave * 8 + (lane >> 3);
      const char* src = (const char*)Wa1T + (size_t)(col0 + crr) * 1024
                        + kq * 128 + (((lane & 7) * 16) ^ ((crr & 7) << 4));
      gll16(src, Bq + kq * 8192 + (rnd * 32 + wave * 8) * 128);
    }
#pragma unroll
  for (int ct = 0; ct < 4; ++ct) {
    float4 b1 = *(const float4*)&ba1[col0 + ct * 16 + g * 4];
    const float* b1p = (const float*)&b1;
#pragma unroll
    for (int q = 0; q < 4; ++q) {
      mv[ct][0][q] += b1p[q];
      mv[ct][1][q] += b1p[q];
    }
  }
  // preload E(knb=0, oct=0) B-fragments (independent of LDS)
  const unsigned short* eb0 =
      E + (size_t)(b_slab * 128 + wave * 32 + r) * 256 + g * 8;
  const unsigned short* eb1 = eb0 + 16 * 256;
  short8v bc0 = *(const short8v*)eb0;
  short8v bc1 = *(const short8v*)eb1;
  __syncthreads();   // Bq(top) ready

  // ---- main loop: 16 knb x 8 k-steps (32-k each), NO barriers ----
  floatx4 acc[4][2];
#pragma unroll
  for (int ct = 0; ct < 4; ++ct) {
    acc[ct][0] = (floatx4)0.0f;
    acc[ct][1] = (floatx4)0.0f;
  }

  for (int knb = 0; knb < 16; ++knb) {
#pragma unroll
    for (int oct = 0; oct < 8; ++oct) {
      // rotating 1-step E prefetch (next oct, or next knb's oct 0)
      short8v bn0 = bc0, bn1 = bc1;
      if (oct < 7) {
        size_t eo = (size_t)knb * 2097152 + (size_t)(oct + 1) * 32;
        bn0 = *(const short8v*)(eb0 + eo);
        bn1 = *(const short8v*)(eb1 + eo);
      } else if (knb < 15) {
        size_t eo = (size_t)(knb + 1) * 2097152;
        bn0 = *(const short8v*)(eb0 + eo);
        bn1 = *(const short8v*)(eb1 + eo);
      }
      const int kq = oct >> 1, kk = oct & 1;
      const int off = (kk * 64 + g * 16) ^ xsw;
      const char* ab = Bq + kq * 8192 + r * 128 + off;
      short8v a0 = *(const short8v*)(ab);
      short8v a1 = *(const short8v*)(ab + 2048);
      short8v a2 = *(const short8v*)(ab + 4096);
      short8v a3 = *(const short8v*)(ab + 6144);
      acc[0][0] = MFMA(a0, bc0, acc[0][0]); acc[0][1] = MFMA(a0, bc1, acc[0][1]);
      acc[1][0] = MFMA(a1, bc0, acc[1][0]); acc[1][1] = MFMA(a1, bc1, acc[1][1]);
      acc[2][0] = MFMA(a2, bc0, acc[2][0]); acc[2][1] = MFMA(a2, bc1, acc[2][1]);
      acc[3][0] = MFMA(a3, bc0, acc[3][0]); acc[3][1] = MFMA(a3, bc1, acc[3][1]);
      bc0 = bn0; bc1 = bn1;
    }
    // epilogue: h = acc + mv; partial logit = sum_cols gelu(h)*Wa2.
    // cols live in registers (ct,q) and lane-group g -> 32 VALU + 2 shfls.
    float v0 = 0.f, v1 = 0.f;
#pragma unroll
    for (int ct = 0; ct < 4; ++ct) {
      float4 w2 = *(const float4*)&Wa2[col0 + ct * 16 + g * 4];
      const float* wp = (const float*)&w2;
#pragma unroll
      for (int q = 0; q < 4; ++q) {
        v0 = fmaf(gelu_poly(acc[ct][0][q] + mv[ct][0][q]), wp[q], v0);
        v1 = fmaf(gelu_poly(acc[ct][1][q] + mv[ct][1][q]), wp[q], v1);
      }
      acc[ct][0] = (floatx4)0.0f;
      acc[ct][1] = (floatx4)0.0f;
    }
    v0 += __shfl_xor(v0, 16); v0 += __shfl_xor(v0, 32);
    v1 += __shfl_xor(v1, 16); v1 += __shfl_xor(v1, 32);
    if (lane < 16) {
      size_t pb = (size_t)nb * BK + (size_t)knb * B_SZ + b_slab * 128 + wave * 32;
      PT[pb + lane] = v0;
      PT[pb + 16 + lane] = v1;
    }
  }
}

// ---------------- K4: sum 32 partials, softmax over 16 neighbors ----------------
__global__ __launch_bounds__(256) void k4_softmax(
    const float* __restrict__ PT, const float* __restrict__ ba2,
    float* __restrict__ attnw) {
  int row = blockIdx.x * 256 + threadIdx.x;
  float logit = ba2[0];
#pragma unroll
  for (int j2 = 0; j2 < 32; ++j2) logit += PT[(size_t)j2 * BK + row];
  float m = logit;
  m = fmaxf(m, __shfl_xor(m, 1)); m = fmaxf(m, __shfl_xor(m, 2));
  m = fmaxf(m, __shfl_xor(m, 4)); m = fmaxf(m, __shfl_xor(m, 8));
  float e = expf(logit - m);
  float s = e;
  s += __shfl_xor(s, 1); s += __shfl_xor(s, 2);
  s += __shfl_xor(s, 4); s += __shfl_xor(s, 8);
  attnw[row] = e / s;
}

// ---------------- K5a: gelu(E @ Wv1 + bv1) weighted by attn, 16-row reduce -> G ----------
// M=131072, N=1024, K=256. Tile 128x256, BK=64, 8 waves (2x4), wave 64x64.
// Epilogue: G[b] = sum over 16 consecutive rows of attn[i]*gelu(h).  G bf16 (8192x1024).
__global__ __launch_bounds__(512) void k5a_gemm(
    const unsigned short* __restrict__ E, const unsigned short* __restrict__ Wv1T,
    const float* __restrict__ bv1, const float* __restrict__ attnw,
    unsigned short* __restrict__ G) {
  __shared__ unsigned short Abuf[128 * 64];   // 16 KB
  __shared__ unsigned short Bbuf[256 * 64];   // 32 KB
  const int tid = threadIdx.x;
  const int wave = tid >> 6, lane = tid & 63, g = lane >> 4, r = lane & 15;
  const int wr = wave >> 2, wc = wave & 3;
  const int nb = blockIdx.x;                  // 0..3
  const int row0 = blockIdx.y * 128;
  const int col0 = nb * 256;
  const int sr = lane >> 3, sc = lane & 7;
  const int swz = ((sc ^ sr) << 4);

  floatx4 acc[4][4];
#pragma unroll
  for (int a = 0; a < 4; ++a)
#pragma unroll
    for (int c2 = 0; c2 < 4; ++c2) acc[a][c2] = (floatx4)0.0f;

  for (int t = 0; t < 4; ++t) {
#pragma unroll
    for (int j = 0; j < 2; ++j) {
      int rowA = j * 64 + wave * 8 + sr;
      const char* src = (const char*)E + ((size_t)(row0 + rowA)) * 512 + t * 128 + swz;
      gll16(src, (char*)Abuf + (j * 512 + wave * 64) * 16);
    }
#pragma unroll
    for (int j = 0; j < 4; ++j) {
      int colB = j * 64 + wave * 8 + sr;
      const char* src = (const char*)Wv1T + ((size_t)(col0 + colB)) * 512 + t * 128 + swz;
      gll16(src, (char*)Bbuf + (j * 512 + wave * 64) * 16);
    }
    __syncthreads();
#pragma unroll
    for (int kk = 0; kk < 2; ++kk) {
      const int off = (kk * 64 + g * 16) ^ ((r & 7) << 4);
      short8v afr[4], bfr[4];
#pragma unroll
      for (int rt = 0; rt < 4; ++rt)
        afr[rt] = *(const short8v*)((const char*)Abuf + (wr * 64 + rt * 16 + r) * 128 + off);
#pragma unroll
      for (int ct = 0; ct < 4; ++ct)
        bfr[ct] = *(const short8v*)((const char*)Bbuf + (wc * 64 + ct * 16 + r) * 128 + off);
#pragma unroll
      for (int rt = 0; rt < 4; ++rt)
#pragma unroll
        for (int ct = 0; ct < 4; ++ct) acc[rt][ct] = MFMA(afr[rt], bfr[ct], acc[rt][ct]);
    }
    __syncthreads();
  }

  // ---- epilogue: weighted gelu + 16-row reduce -> G ----
  float aw[4][4];
#pragma unroll
  for (int rt = 0; rt < 4; ++rt)
#pragma unroll
    for (int q = 0; q < 4; ++q)
      aw[rt][q] = attnw[row0 + wr * 64 + rt * 16 + g * 4 + q];
#pragma unroll
  for (int ct = 0; ct < 4; ++ct) {
    int col = col0 + wc * 64 + ct * 16 + r;
    float b1 = bv1[col];
#pragma unroll
    for (int rt = 0; rt < 4; ++rt) {
      float s = 0.f;
#pragma unroll
      for (int q = 0; q < 4; ++q)
        s = fmaf(aw[rt][q], gelu_poly(acc[rt][ct][q] + b1), s);
      s += __shfl_xor(s, 16);
      s += __shfl_xor(s, 32);
      if (g == 0)
        G[(size_t)((row0 >> 4) + wr * 4 + rt) * 1024 + col] = f2bf(s);
    }
  }
}

// ---------------- K5b: out = G @ Wv2 + bv2  (8192 x 1024 x 256) ----------------
// Tile 64x128, BK=64, 4 waves (2x2), wave 32x64.
__global__ __launch_bounds__(256) void k5b_gemm(
    const unsigned short* __restrict__ G, const unsigned short* __restrict__ Wv2T,
    const float* __restrict__ bv2, float* __restrict__ out) {
  __shared__ unsigned short Abuf[64 * 64];    // 8 KB
  __shared__ unsigned short Bbuf[128 * 64];   // 16 KB
  const int tid = threadIdx.x;
  const int wave = tid >> 6, lane = tid & 63, g = lane >> 4, r = lane & 15;
  const int wr = wave >> 1, wc = wave & 1;
  const int col0 = blockIdx.x * 128;
  const int row0 = blockIdx.y * 64;
  const int sr = lane >> 3, sc = lane & 7;
  const int swz = ((sc ^ sr) << 4);

  floatx4 acc[2][4];
#pragma unroll
  for (int a = 0; a < 2; ++a)
#pragma unroll
    for (int c2 = 0; c2 < 4; ++c2) acc[a][c2] = (floatx4)0.0f;

  for (int t = 0; t < 16; ++t) {
#pragma unroll
    for (int j = 0; j < 2; ++j) {
      int rowA = j * 32 + wave * 8 + sr;
      const char* src = (const char*)G + ((size_t)(row0 + rowA)) * 2048 + t * 128 + swz;
      gll16(src, (char*)Abuf + (j * 256 + wave * 64) * 16);
    }
#pragma unroll
    for (int j = 0; j < 4; ++j) {
      int colB = j * 32 + wave * 8 + sr;
      const char* src = (const char*)Wv2T + ((size_t)(col0 + colB)) * 2048 + t * 128 + swz;
      gll16(src, (char*)Bbuf + (j * 256 + wave * 64) * 16);
    }
    __syncthreads();
#pragma unroll
    for (int kk = 0; kk < 2; ++kk) {
      const int off = (kk * 64 + g * 16) ^ ((r & 7) << 4);
      short8v afr[2], bfr[4];
#pragma unroll
      for (int rt = 0; rt < 2; ++rt)
        afr[rt] = *(const short8v*)((const char*)Abuf + (wr * 32 + rt * 16 + r) * 128 + off);
#pragma unroll
      for (int ct = 0; ct < 4; ++ct)
        bfr[ct] = *(const short8v*)((const char*)Bbuf + (wc * 64 + ct * 16 + r) * 128 + off);
#pragma unroll
      for (int rt = 0; rt < 2; ++rt)
#pragma unroll
        for (int ct = 0; ct < 4; ++ct) acc[rt][ct] = MFMA(afr[rt], bfr[ct], acc[rt][ct]);
    }
    __syncthreads();
  }

#pragma unroll
  for (int ct = 0; ct < 4; ++ct) {
    int col = col0 + wc * 64 + ct * 16 + r;
    float b = bv2[col];
#pragma unroll
    for (int rt = 0; rt < 2; ++rt)
#pragma unroll
      for (int q = 0; q < 4; ++q)
        out[(size_t)(row0 + wr * 32 + rt * 16 + g * 4 + q) * ED + col] =
            acc[rt][ct][q] + b;
  }
}

extern "C" void kernel_launch(void* const* d_in, const int* in_sizes, int n_in,
                              void* d_out, int out_size, void* d_ws, size_t ws_size,
                              hipStream_t stream) {
  const float* self_obs = (const float*)d_in[0];
  const float* obs = (const float*)d_in[1];
  const float* We1 = (const float*)d_in[2];
  const float* be1 = (const float*)d_in[3];
  const float* We2 = (const float*)d_in[4];
  const float* be2 = (const float*)d_in[5];
  const float* Wv1 = (const float*)d_in[6];
  const float* bv1 = (const float*)d_in[7];
  const float* Wv2 = (const float*)d_in[8];
  const float* bv2 = (const float*)d_in[9];
  const float* Wa1 = (const float*)d_in[10];
  const float* ba1 = (const float*)d_in[11];
  const float* Wa2 = (const float*)d_in[12];
  const float* ba2 = (const float*)d_in[13];
  float* out = (float*)d_out;

  char* ws = (char*)d_ws;
  size_t off = 0;
  auto alloc = [&](size_t bytes) {
    char* p = ws + off;
    off += (bytes + 255) & ~(size_t)255;
    return p;
  };
  unsigned short* E    = (unsigned short*)alloc((size_t)BK * ED * 2);
  unsigned short* M    = (unsigned short*)alloc((size_t)B_SZ * ED * 2);
  float*          attn = (float*)alloc((size_t)BK * 4);
  float*          PT   = (float*)alloc((size_t)32 * BK * 4);
  unsigned short* We1T = (unsigned short*)alloc(128 * 512 * 2);
  unsigned short* We2T = (unsigned short*)alloc(512 * 256 * 2);
  unsigned short* Wv1T = (unsigned short*)alloc(256 * 1024 * 2);
  unsigned short* Wv2T = (unsigned short*)alloc(1024 * 256 * 2);
  unsigned short* Wa1T = (unsigned short*)alloc(512 * 2048 * 2);
  // G (8192x1024 bf16, 16 MB) aliases PT (dead after k4; sizes match exactly)
  unsigned short* G    = (unsigned short*)PT;

  wt_kernel<<<(128 * 512 + 255) / 256, 256, 0, stream>>>(We1, We1T, 128, 512);
  wt_kernel<<<(512 * 256 + 255) / 256, 256, 0, stream>>>(We2, We2T, 512, 256);
  wt_kernel<<<(256 * 1024 + 255) / 256, 256, 0, stream>>>(Wv1, Wv1T, 256, 1024);
  wt_kernel<<<(1024 * 256 + 255) / 256, 256, 0, stream>>>(Wv2, Wv2T, 1024, 256);
  wt_kernel<<<(512 * 2048 + 255) / 256, 256, 0, stream>>>(Wa1, Wa1T, 512, 2048);

  k1_kernel<<<BK / 64, 256, 0, stream>>>(self_obs, obs, We1T, be1, We2T, be2, E, M);
  k3_fused<<<2048, 256, 0, stream>>>(E, M, Wa1T, ba1, Wa2, PT);
  k4_softmax<<<BK / 256, 256, 0, stream>>>(PT, ba2, attn);
  k5a_gemm<<<dim3(4, 1024), 512, 0, stream>>>(E, Wv1T, bv1, attn, G);
  k5b_gemm<<<dim3(2, 128), 256, 0, stream>>>(G, Wv2T, bv2, out);
}

// Round 2
// 504.195 us; speedup vs baseline: 2.0367x; 2.0367x over previous
//
#include <hip/hip_runtime.h>
#include <hip/hip_bf16.h>

#define B_SZ 8192
#define KNB 16
#define BK 131072
#define ED 256

typedef __attribute__((ext_vector_type(8))) short short8v;
typedef __attribute__((ext_vector_type(4))) float floatx4;

static __device__ __forceinline__ unsigned short f2bf(float f) {
  unsigned int u = __float_as_uint(f);
  u = (u + 0x7FFFu + ((u >> 16) & 1u)) >> 16;
  return (unsigned short)u;
}
static __device__ __forceinline__ float bf2f(unsigned short u) {
  return __uint_as_float(((unsigned int)u) << 16);
}
static __device__ __forceinline__ float gelu_erf(float x) {
  return 0.5f * x * (1.0f + erff(x * 0.70710678118654752f));
}
// gelu via odd Taylor of erf(x/sqrt(2)); exact to ~1e-9 for |x|<0.5 (FF2/FF3 have |x|<0.15)
static __device__ __forceinline__ float gelu_poly(float x) {
  float t = x * x;
  float p = fmaf(t, fmaf(t, fmaf(t, fmaf(t, 2.8935185185e-4f, -2.9761904762e-3f),
                                 2.5e-2f), -1.6666666667e-1f), 1.0f);
  return 0.5f * x * fmaf(0.79788456080286536f * x, p, 1.0f);
}

#define MFMA(a, b, c) __builtin_amdgcn_mfma_f32_16x16x32_bf16((a), (b), (c), 0, 0, 0)

// async global->LDS, 16B per lane, dest = wave-uniform base + lane*16
static __device__ __forceinline__ void gll16(const void* g, void* l) {
  __builtin_amdgcn_global_load_lds(
      (const __attribute__((address_space(1))) unsigned int*)g,
      (__attribute__((address_space(3))) unsigned int*)l, 16, 0, 0);
}

// ---------------- prep: W[K][N] f32 -> WT[N][K] bf16 ----------------
__global__ void wt_kernel(const float* __restrict__ W, unsigned short* __restrict__ WT,
                          int K, int N) {
  int idx = blockIdx.x * 256 + threadIdx.x;
  if (idx >= K * N) return;
  int n = idx / K, k = idx - n * K;
  WT[idx] = f2bf(W[(size_t)k * N + n]);
}

// ---------------- K1: FF1 (gathered input) -> E (bf16), M (bf16) ----------------
__global__ __launch_bounds__(256) void k1_kernel(
    const float* __restrict__ self_obs, const float* __restrict__ obs,
    const unsigned short* __restrict__ We1T, const float* __restrict__ be1,
    const unsigned short* __restrict__ We2T, const float* __restrict__ be2,
    unsigned short* __restrict__ E, unsigned short* __restrict__ M) {
  __shared__ unsigned short Xt[64][136];   // 64 x 128 bf16, +8 pad
  __shared__ unsigned short Ht[64][136];   // 64 x 128 bf16 hidden chunk
  const int tid = threadIdx.x;
  const int wave = tid >> 6, lane = tid & 63, g = lane >> 4, r = lane & 15;
  const int row0 = blockIdx.x * 64;

  // stage gathered X tile, f32 -> bf16
#pragma unroll
  for (int p = 0; p < 8; ++p) {
    int e4 = (p * 256 + tid) * 4;
    int i = e4 >> 7, c = e4 & 127;
    int gi = row0 + i;
    const float* src;
    if (c < 64) src = self_obs + (size_t)(gi & (B_SZ - 1)) * 64 + c;
    else        src = obs + (size_t)(gi >> 4) * 1088 + 64 + (gi & 15) * 64 + (c - 64);
    float4 v = *(const float4*)src;
    ushort4 w;
    w.x = f2bf(v.x); w.y = f2bf(v.y); w.z = f2bf(v.z); w.w = f2bf(v.w);
    *(ushort4*)&Xt[i][c] = w;
  }
  __syncthreads();

  floatx4 eacc[4][4];  // [rt][ct]
#pragma unroll
  for (int a = 0; a < 4; ++a)
#pragma unroll
    for (int c2 = 0; c2 < 4; ++c2) eacc[a][c2] = (floatx4)0.0f;

  for (int chunk = 0; chunk < 4; ++chunk) {
    const int hbase = chunk * 128;
    floatx4 hacc[2][4];  // [ctl][rt]
#pragma unroll
    for (int a = 0; a < 2; ++a)
#pragma unroll
      for (int c2 = 0; c2 < 4; ++c2) hacc[a][c2] = (floatx4)0.0f;

#pragma unroll
    for (int kk = 0; kk < 4; ++kk) {   // K = 128
      short8v afr[4];
#pragma unroll
      for (int rt = 0; rt < 4; ++rt)
        afr[rt] = *(const short8v*)&Xt[rt * 16 + r][kk * 32 + g * 8];
#pragma unroll
      for (int ctl = 0; ctl < 2; ++ctl) {
        int col = hbase + wave * 32 + ctl * 16 + r;
        short8v bfr = *(const short8v*)&We1T[(size_t)col * 128 + kk * 32 + g * 8];
#pragma unroll
        for (int rt = 0; rt < 4; ++rt) hacc[ctl][rt] = MFMA(afr[rt], bfr, hacc[ctl][rt]);
      }
    }
    // bias + gelu(erf) -> Ht
#pragma unroll
    for (int ctl = 0; ctl < 2; ++ctl) {
      int col = hbase + wave * 32 + ctl * 16 + r;
      float bias = be1[col];
#pragma unroll
      for (int rt = 0; rt < 4; ++rt)
#pragma unroll
        for (int q = 0; q < 4; ++q) {
          float h = gelu_erf(hacc[ctl][rt][q] + bias);
          Ht[rt * 16 + g * 4 + q][wave * 32 + ctl * 16 + r] = f2bf(h);
        }
    }
    __syncthreads();
    // layer2 partial: E += gelu(H) @ We2[hbase:hbase+128, :]
#pragma unroll
    for (int kk = 0; kk < 4; ++kk) {
      short8v afr[4];
#pragma unroll
      for (int rt = 0; rt < 4; ++rt)
        afr[rt] = *(const short8v*)&Ht[rt * 16 + r][kk * 32 + g * 8];
#pragma unroll
      for (int ct = 0; ct < 4; ++ct) {
        int col = wave * 64 + ct * 16 + r;
        short8v bfr = *(const short8v*)&We2T[(size_t)col * 512 + hbase + kk * 32 + g * 8];
#pragma unroll
        for (int rt = 0; rt < 4; ++rt) eacc[rt][ct] = MFMA(afr[rt], bfr, eacc[rt][ct]);
      }
    }
    __syncthreads();
  }

  // epilogue: +bias, store E (bf16), 16-row group mean -> M
#pragma unroll
  for (int ct = 0; ct < 4; ++ct) {
    int col = wave * 64 + ct * 16 + r;
    float bias = be2[col];
#pragma unroll
    for (int rt = 0; rt < 4; ++rt) {
      float msum = 0.f;
#pragma unroll
      for (int q = 0; q < 4; ++q) {
        float e = eacc[rt][ct][q] + bias;
        int row = rt * 16 + g * 4 + q;
        E[(size_t)(row0 + row) * ED + col] = f2bf(e);
        msum += e;
      }
      msum += __shfl_xor(msum, 16);
      msum += __shfl_xor(msum, 32);
      if (g == 0) {
        int b = (row0 >> 4) + rt;
        M[(size_t)b * ED + col] = f2bf(msum * 0.0625f);
      }
    }
  }
}

// ---------------- K2: MV = M @ Wa1_bot + ba1  (8192 x 2048 x 256), bf16 out ------
// Tile 128x256, BK=64, 8 waves (2x4), wave 64x64. Same skeleton as k5a.
__global__ __launch_bounds__(512) void k2_mv(
    const unsigned short* __restrict__ M, const unsigned short* __restrict__ Wa1T,
    const float* __restrict__ ba1, unsigned short* __restrict__ MV) {
  __shared__ unsigned short Abuf[128 * 64];   // 16 KB
  __shared__ unsigned short Bbuf[256 * 64];   // 32 KB
  const int tid = threadIdx.x;
  const int wave = tid >> 6, lane = tid & 63, g = lane >> 4, r = lane & 15;
  const int wr = wave >> 2, wc = wave & 3;
  const int row0 = blockIdx.y * 128;
  const int col0 = blockIdx.x * 256;
  const int sr = lane >> 3, sc = lane & 7;
  const int swz = ((sc ^ sr) << 4);

  floatx4 acc[4][4];
#pragma unroll
  for (int a = 0; a < 4; ++a)
#pragma unroll
    for (int c2 = 0; c2 < 4; ++c2) acc[a][c2] = (floatx4)0.0f;

  for (int t = 0; t < 4; ++t) {
#pragma unroll
    for (int j = 0; j < 2; ++j) {
      int rowA = j * 64 + wave * 8 + sr;
      const char* src = (const char*)M + ((size_t)(row0 + rowA)) * 512 + t * 128 + swz;
      gll16(src, (char*)Abuf + (j * 512 + wave * 64) * 16);
    }
#pragma unroll
    for (int j = 0; j < 4; ++j) {
      int colB = j * 64 + wave * 8 + sr;
      // bottom half of Wa1T rows (k = 256..511 -> byte offset +512 of each 1KB col)
      const char* src = (const char*)Wa1T + ((size_t)(col0 + colB)) * 1024 + 512
                        + t * 128 + swz;
      gll16(src, (char*)Bbuf + (j * 512 + wave * 64) * 16);
    }
    __syncthreads();
#pragma unroll
    for (int kk = 0; kk < 2; ++kk) {
      const int off = (kk * 64 + g * 16) ^ ((r & 7) << 4);
      short8v afr[4], bfr[4];
#pragma unroll
      for (int rt = 0; rt < 4; ++rt)
        afr[rt] = *(const short8v*)((const char*)Abuf + (wr * 64 + rt * 16 + r) * 128 + off);
#pragma unroll
      for (int ct = 0; ct < 4; ++ct)
        bfr[ct] = *(const short8v*)((const char*)Bbuf + (wc * 64 + ct * 16 + r) * 128 + off);
#pragma unroll
      for (int rt = 0; rt < 4; ++rt)
#pragma unroll
        for (int ct = 0; ct < 4; ++ct) acc[rt][ct] = MFMA(afr[rt], bfr[ct], acc[rt][ct]);
    }
    __syncthreads();
  }

#pragma unroll
  for (int ct = 0; ct < 4; ++ct) {
    int col = col0 + wc * 64 + ct * 16 + r;
    float b1 = ba1[col];
#pragma unroll
    for (int rt = 0; rt < 4; ++rt)
#pragma unroll
      for (int q = 0; q < 4; ++q)
        MV[(size_t)(row0 + wr * 64 + rt * 16 + g * 4 + q) * 2048 + col] =
            f2bf(acc[rt][ct][q] + b1);
  }
}

// ---------------- K3: attention logits, E-resident-in-registers design ----------
// Block = 8 waves (512 thr); wave w owns j = bid*8+w; its 16 rows are i = r*8192+j
// (knb = lane r), pairing E[i] with MV[i & 8191] = MV[j] per the reference tiling.
// E fragments (16 rows x 256 k = 32 VGPR) are loaded ONCE -> E read exactly once
// globally (64 MB total, no cross-block reuse needed). Loop over all 2048 attn cols
// in 64-col chunks; only Wa1_top chunks staged to LDS (32 KB, double-buffered,
// stage-before-compute so the barrier vmcnt drain lands after ~2000 cyc of MFMA).
// Logit completes in-block -> write final L[i]; PT partials eliminated.
__global__ __launch_bounds__(512, 4) void k3_fused(
    const unsigned short* __restrict__ E, const unsigned short* __restrict__ MV,
    const unsigned short* __restrict__ Wa1T, const float* __restrict__ Wa2,
    float* __restrict__ L) {
  __shared__ char Bq[65536];   // 2 bufs x [64 cols][512B k], row-XOR swizzled
  const int tid = threadIdx.x;
  const int wave = tid >> 6, lane = tid & 63, g = lane >> 4, r = lane & 15;
  const int j = blockIdx.x * 8 + wave;
  const int xsw = (r & 7) << 4;

  // ---- E preload: rows i = r*8192 + j, full K=256, 8x short8v = 32 VGPR ----
  const unsigned short* ebase = E + ((size_t)r * 8192 + j) * 256 + g * 8;
  short8v er[8];
#pragma unroll
  for (int kk = 0; kk < 8; ++kk) er[kk] = *(const short8v*)(ebase + kk * 32);

  // staging lane constants: call m covers cols 2m,2m+1 (512B each) of the chunk
  const int scol2 = lane >> 5;
  const int sbyte = (lane & 31) * 16;

  // stage chunk c into buffer bufsel (4 gll16 calls per wave, 32 per block)
  auto STAGE = [&](int c, int bufsel) {
#pragma unroll
    for (int cc = 0; cc < 4; ++cc) {
      int m = wave * 4 + cc;
      int col = c * 64 + m * 2 + scol2;
      const char* src = (const char*)Wa1T + (size_t)col * 1024
                        + (sbyte ^ ((col & 7) << 4));
      gll16(src, Bq + bufsel * 32768 + m * 1024);
    }
  };

  STAGE(0, 0);
  __syncthreads();

  float lg = 0.f;
  const unsigned short* mvrow = MV + (size_t)j * 2048;

  for (int c = 0; c < 32; ++c) {
    if (c + 1 < 32) STAGE(c + 1, (c + 1) & 1);
    // mv (bf16) + Wa2 for this chunk; uniform across the 16 r-lanes (broadcast)
    ushort4 mvu[4];
    float4 w2[4];
#pragma unroll
    for (int ct = 0; ct < 4; ++ct) {
      mvu[ct] = *(const ushort4*)(mvrow + c * 64 + ct * 16 + g * 4);
      w2[ct] = *(const float4*)&Wa2[c * 64 + ct * 16 + g * 4];
    }
    floatx4 acc[4];
#pragma unroll
    for (int ct = 0; ct < 4; ++ct) acc[ct] = (floatx4)0.0f;
    const char* bufb = Bq + (c & 1) * 32768;
#pragma unroll
    for (int kk = 0; kk < 8; ++kk) {
      const int off = (kk * 64 + g * 16) ^ xsw;
#pragma unroll
      for (int ct = 0; ct < 4; ++ct) {
        short8v a = *(const short8v*)(bufb + (ct * 16 + r) * 512 + off);
        acc[ct] = MFMA(a, er[kk], acc[ct]);
      }
    }
    // chunk epilogue: h = acc + mv; lg += gelu(h) . Wa2  (no shuffles)
#pragma unroll
    for (int ct = 0; ct < 4; ++ct) {
      const float* wp = (const float*)&w2[ct];
      lg = fmaf(gelu_poly(acc[ct][0] + bf2f(mvu[ct].x)), wp[0], lg);
      lg = fmaf(gelu_poly(acc[ct][1] + bf2f(mvu[ct].y)), wp[1], lg);
      lg = fmaf(gelu_poly(acc[ct][2] + bf2f(mvu[ct].z)), wp[2], lg);
      lg = fmaf(gelu_poly(acc[ct][3] + bf2f(mvu[ct].w)), wp[3], lg);
    }
    __syncthreads();   // stage(c+1) landed long ago; also fences buf reads
  }

  // final reduce across the 4 g-groups (disjoint col subsets), write logit
  lg += __shfl_xor(lg, 16);
  lg += __shfl_xor(lg, 32);
  if (g == 0) L[(size_t)r * 8192 + j] = lg;
}

// ---------------- K4: softmax over 16 neighbors (consecutive rows) ----------------
__global__ __launch_bounds__(256) void k4_softmax(
    const float* __restrict__ L, const float* __restrict__ ba2,
    float* __restrict__ attnw) {
  int row = blockIdx.x * 256 + threadIdx.x;
  float logit = L[row] + ba2[0];
  float m = logit;
  m = fmaxf(m, __shfl_xor(m, 1)); m = fmaxf(m, __shfl_xor(m, 2));
  m = fmaxf(m, __shfl_xor(m, 4)); m = fmaxf(m, __shfl_xor(m, 8));
  float e = expf(logit - m);
  float s = e;
  s += __shfl_xor(s, 1); s += __shfl_xor(s, 2);
  s += __shfl_xor(s, 4); s += __shfl_xor(s, 8);
  attnw[row] = e / s;
}

// ---------------- K5a: gelu(E @ Wv1 + bv1) weighted by attn, 16-row reduce -> G ----------
// M=131072, N=1024, K=256. Tile 128x256, BK=64, 8 waves (2x4), wave 64x64.
// Epilogue: G[b] = sum over 16 consecutive rows of attn[i]*gelu(h).  G bf16 (8192x1024).
__global__ __launch_bounds__(512) void k5a_gemm(
    const unsigned short* __restrict__ E, const unsigned short* __restrict__ Wv1T,
    const float* __restrict__ bv1, const float* __restrict__ attnw,
    unsigned short* __restrict__ G) {
  __shared__ unsigned short Abuf[128 * 64];   // 16 KB
  __shared__ unsigned short Bbuf[256 * 64];   // 32 KB
  const int tid = threadIdx.x;
  const int wave = tid >> 6, lane = tid & 63, g = lane >> 4, r = lane & 15;
  const int wr = wave >> 2, wc = wave & 3;
  const int nb = blockIdx.x;                  // 0..3
  const int row0 = blockIdx.y * 128;
  const int col0 = nb * 256;
  const int sr = lane >> 3, sc = lane & 7;
  const int swz = ((sc ^ sr) << 4);

  floatx4 acc[4][4];
#pragma unroll
  for (int a = 0; a < 4; ++a)
#pragma unroll
    for (int c2 = 0; c2 < 4; ++c2) acc[a][c2] = (floatx4)0.0f;

  for (int t = 0; t < 4; ++t) {
#pragma unroll
    for (int j = 0; j < 2; ++j) {
      int rowA = j * 64 + wave * 8 + sr;
      const char* src = (const char*)E + ((size_t)(row0 + rowA)) * 512 + t * 128 + swz;
      gll16(src, (char*)Abuf + (j * 512 + wave * 64) * 16);
    }
#pragma unroll
    for (int j = 0; j < 4; ++j) {
      int colB = j * 64 + wave * 8 + sr;
      const char* src = (const char*)Wv1T + ((size_t)(col0 + colB)) * 512 + t * 128 + swz;
      gll16(src, (char*)Bbuf + (j * 512 + wave * 64) * 16);
    }
    __syncthreads();
#pragma unroll
    for (int kk = 0; kk < 2; ++kk) {
      const int off = (kk * 64 + g * 16) ^ ((r & 7) << 4);
      short8v afr[4], bfr[4];
#pragma unroll
      for (int rt = 0; rt < 4; ++rt)
        afr[rt] = *(const short8v*)((const char*)Abuf + (wr * 64 + rt * 16 + r) * 128 + off);
#pragma unroll
      for (int ct = 0; ct < 4; ++ct)
        bfr[ct] = *(const short8v*)((const char*)Bbuf + (wc * 64 + ct * 16 + r) * 128 + off);
#pragma unroll
      for (int rt = 0; rt < 4; ++rt)
#pragma unroll
        for (int ct = 0; ct < 4; ++ct) acc[rt][ct] = MFMA(afr[rt], bfr[ct], acc[rt][ct]);
    }
    __syncthreads();
  }

  // ---- epilogue: weighted gelu + 16-row reduce -> G ----
  float aw[4][4];
#pragma unroll
  for (int rt = 0; rt < 4; ++rt)
#pragma unroll
    for (int q = 0; q < 4; ++q)
      aw[rt][q] = attnw[row0 + wr * 64 + rt * 16 + g * 4 + q];
#pragma unroll
  for (int ct = 0; ct < 4; ++ct) {
    int col = col0 + wc * 64 + ct * 16 + r;
    float b1 = bv1[col];
#pragma unroll
    for (int rt = 0; rt < 4; ++rt) {
      float s = 0.f;
#pragma unroll
      for (int q = 0; q < 4; ++q)
        s = fmaf(aw[rt][q], gelu_poly(acc[rt][ct][q] + b1), s);
      s += __shfl_xor(s, 16);
      s += __shfl_xor(s, 32);
      if (g == 0)
        G[(size_t)((row0 >> 4) + wr * 4 + rt) * 1024 + col] = f2bf(s);
    }
  }
}

// ---------------- K5b: out = G @ Wv2 + bv2  (8192 x 1024 x 256) ----------------
// Tile 64x128, BK=64, 4 waves (2x2), wave 32x64.
__global__ __launch_bounds__(256) void k5b_gemm(
    const unsigned short* __restrict__ G, const unsigned short* __restrict__ Wv2T,
    const float* __restrict__ bv2, float* __restrict__ out) {
  __shared__ unsigned short Abuf[64 * 64];    // 8 KB
  __shared__ unsigned short Bbuf[128 * 64];   // 16 KB
  const int tid = threadIdx.x;
  const int wave = tid >> 6, lane = tid & 63, g = lane >> 4, r = lane & 15;
  const int wr = wave >> 1, wc = wave & 1;
  const int col0 = blockIdx.x * 128;
  const int row0 = blockIdx.y * 64;
  const int sr = lane >> 3, sc = lane & 7;
  const int swz = ((sc ^ sr) << 4);

  floatx4 acc[2][4];
#pragma unroll
  for (int a = 0; a < 2; ++a)
#pragma unroll
    for (int c2 = 0; c2 < 4; ++c2) acc[a][c2] = (floatx4)0.0f;

  for (int t = 0; t < 16; ++t) {
#pragma unroll
    for (int j = 0; j < 2; ++j) {
      int rowA = j * 32 + wave * 8 + sr;
      const char* src = (const char*)G + ((size_t)(row0 + rowA)) * 2048 + t * 128 + swz;
      gll16(src, (char*)Abuf + (j * 256 + wave * 64) * 16);
    }
#pragma unroll
    for (int j = 0; j < 4; ++j) {
      int colB = j * 32 + wave * 8 + sr;
      const char* src = (const char*)Wv2T + ((size_t)(col0 + colB)) * 2048 + t * 128 + swz;
      gll16(src, (char*)Bbuf + (j * 256 + wave * 64) * 16);
    }
    __syncthreads();
#pragma unroll
    for (int kk = 0; kk < 2; ++kk) {
      const int off = (kk * 64 + g * 16) ^ ((r & 7) << 4);
      short8v afr[2], bfr[4];
#pragma unroll
      for (int rt = 0; rt < 2; ++rt)
        afr[rt] = *(const short8v*)((const char*)Abuf + (wr * 32 + rt * 16 + r) * 128 + off);
#pragma unroll
      for (int ct = 0; ct < 4; ++ct)
        bfr[ct] = *(const short8v*)((const char*)Bbuf + (wc * 64 + ct * 16 + r) * 128 + off);
#pragma unroll
      for (int rt = 0; rt < 2; ++rt)
#pragma unroll
        for (int ct = 0; ct < 4; ++ct) acc[rt][ct] = MFMA(afr[rt], bfr[ct], acc[rt][ct]);
    }
    __syncthreads();
  }

#pragma unroll
  for (int ct = 0; ct < 4; ++ct) {
    int col = col0 + wc * 64 + ct * 16 + r;
    float b = bv2[col];
#pragma unroll
    for (int rt = 0; rt < 2; ++rt)
#pragma unroll
      for (int q = 0; q < 4; ++q)
        out[(size_t)(row0 + wr * 32 + rt * 16 + g * 4 + q) * ED + col] =
            acc[rt][ct][q] + b;
  }
}

extern "C" void kernel_launch(void* const* d_in, const int* in_sizes, int n_in,
                              void* d_out, int out_size, void* d_ws, size_t ws_size,
                              hipStream_t stream) {
  const float* self_obs = (const float*)d_in[0];
  const float* obs = (const float*)d_in[1];
  const float* We1 = (const float*)d_in[2];
  const float* be1 = (const float*)d_in[3];
  const float* We2 = (const float*)d_in[4];
  const float* be2 = (const float*)d_in[5];
  const float* Wv1 = (const float*)d_in[6];
  const float* bv1 = (const float*)d_in[7];
  const float* Wv2 = (const float*)d_in[8];
  const float* bv2 = (const float*)d_in[9];
  const float* Wa1 = (const float*)d_in[10];
  const float* ba1 = (const float*)d_in[11];
  const float* Wa2 = (const float*)d_in[12];
  const float* ba2 = (const float*)d_in[13];
  float* out = (float*)d_out;

  char* ws = (char*)d_ws;
  size_t off = 0;
  auto alloc = [&](size_t bytes) {
    char* p = ws + off;
    off += (bytes + 255) & ~(size_t)255;
    return p;
  };
  unsigned short* E    = (unsigned short*)alloc((size_t)BK * ED * 2);      // 64 MB
  unsigned short* M    = (unsigned short*)alloc((size_t)B_SZ * ED * 2);    // 4 MB
  float*          attn = (float*)alloc((size_t)BK * 4);                    // 0.5 MB
  unsigned short* MV   = (unsigned short*)alloc((size_t)B_SZ * 2048 * 2);  // 32 MB
  float*          L    = (float*)alloc((size_t)BK * 4);                    // 0.5 MB
  unsigned short* We1T = (unsigned short*)alloc(128 * 512 * 2);
  unsigned short* We2T = (unsigned short*)alloc(512 * 256 * 2);
  unsigned short* Wv1T = (unsigned short*)alloc(256 * 1024 * 2);
  unsigned short* Wv2T = (unsigned short*)alloc(1024 * 256 * 2);
  unsigned short* Wa1T = (unsigned short*)alloc(512 * 2048 * 2);
  // G (8192x1024 bf16, 16 MB) aliases MV (32 MB, dead after k3)
  unsigned short* G    = (unsigned short*)MV;

  wt_kernel<<<(128 * 512 + 255) / 256, 256, 0, stream>>>(We1, We1T, 128, 512);
  wt_kernel<<<(512 * 256 + 255) / 256, 256, 0, stream>>>(We2, We2T, 512, 256);
  wt_kernel<<<(256 * 1024 + 255) / 256, 256, 0, stream>>>(Wv1, Wv1T, 256, 1024);
  wt_kernel<<<(1024 * 256 + 255) / 256, 256, 0, stream>>>(Wv2, Wv2T, 1024, 256);
  wt_kernel<<<(512 * 2048 + 255) / 256, 256, 0, stream>>>(Wa1, Wa1T, 512, 2048);

  k1_kernel<<<BK / 64, 256, 0, stream>>>(self_obs, obs, We1T, be1, We2T, be2, E, M);
  k2_mv<<<dim3(8, 64), 512, 0, stream>>>(M, Wa1T, ba1, MV);
  k3_fused<<<B_SZ / 8, 512, 0, stream>>>(E, MV, Wa1T, Wa2, L);
  k4_softmax<<<BK / 256, 256, 0, stream>>>(L, ba2, attn);
  k5a_gemm<<<dim3(4, 1024), 512, 0, stream>>>(E, Wv1T, bv1, attn, G);
  k5b_gemm<<<dim3(2, 128), 256, 0, stream>>>(G, Wv2T, bv2, out);
}

// Round 3
// 484.194 us; speedup vs baseline: 2.1208x; 1.0413x over previous
//
#include <hip/hip_runtime.h>
#include <hip/hip_bf16.h>

#define B_SZ 8192
#define KNB 16
#define BK 131072
#define ED 256

typedef __attribute__((ext_vector_type(8))) short short8v;
typedef __attribute__((ext_vector_type(4))) float floatx4;

static __device__ __forceinline__ unsigned short f2bf(float f) {
  unsigned int u = __float_as_uint(f);
  u = (u + 0x7FFFu + ((u >> 16) & 1u)) >> 16;
  return (unsigned short)u;
}
static __device__ __forceinline__ float bf2f(unsigned short u) {
  return __uint_as_float(((unsigned int)u) << 16);
}
static __device__ __forceinline__ float gelu_erf(float x) {
  return 0.5f * x * (1.0f + erff(x * 0.70710678118654752f));
}
// gelu via odd Taylor of erf(x/sqrt(2)); exact to ~1e-9 for |x|<0.5 (FF2/FF3 have |x|<0.15)
static __device__ __forceinline__ float gelu_poly(float x) {
  float t = x * x;
  float p = fmaf(t, fmaf(t, fmaf(t, fmaf(t, 2.8935185185e-4f, -2.9761904762e-3f),
                                 2.5e-2f), -1.6666666667e-1f), 1.0f);
  return 0.5f * x * fmaf(0.79788456080286536f * x, p, 1.0f);
}

#define MFMA(a, b, c) __builtin_amdgcn_mfma_f32_16x16x32_bf16((a), (b), (c), 0, 0, 0)

// async global->LDS, 16B per lane, dest = wave-uniform base + lane*16
static __device__ __forceinline__ void gll16(const void* g, void* l) {
  __builtin_amdgcn_global_load_lds(
      (const __attribute__((address_space(1))) unsigned int*)g,
      (__attribute__((address_space(3))) unsigned int*)l, 16, 0, 0);
}

// ---------------- prep: W[K][N] f32 -> WT[N][K] bf16 ----------------
__global__ void wt_kernel(const float* __restrict__ W, unsigned short* __restrict__ WT,
                          int K, int N) {
  int idx = blockIdx.x * 256 + threadIdx.x;
  if (idx >= K * N) return;
  int n = idx / K, k = idx - n * K;
  WT[idx] = f2bf(W[(size_t)k * N + n]);
}

// ---------------- prep: Wa1 top half (k=0..255) -> MFMA-fragment order ----------------
// frag f = ctile*8 + kk (ctile 0..127 over 2048 cols, kk 0..7 over K=256).
// Within frag: short index = lane*8 + i, element = Wa1[k = kk*32 + (lane>>4)*8 + i]
//                                              [col = ctile*16 + (lane&15)].
// A wave's ds_read_b128 of one frag is then a contiguous 1 KB: conflict-free.
__global__ void wa1f_kernel(const float* __restrict__ Wa1,
                            unsigned short* __restrict__ Wa1F) {
  int idx = blockIdx.x * 256 + threadIdx.x;   // 2048*256 = 524288 elements
  int f = idx >> 9;          // frag id 0..1023
  int w = idx & 511;         // short index within frag
  int ln = w >> 3, i = w & 7;
  int ctile = f >> 3, kk = f & 7;
  int col = ctile * 16 + (ln & 15);
  int k = kk * 32 + (ln >> 4) * 8 + i;
  Wa1F[idx] = f2bf(Wa1[(size_t)k * 2048 + col]);
}

// ---------------- K1: FF1 (gathered input) -> E (bf16), M (bf16) ----------------
__global__ __launch_bounds__(256) void k1_kernel(
    const float* __restrict__ self_obs, const float* __restrict__ obs,
    const unsigned short* __restrict__ We1T, const float* __restrict__ be1,
    const unsigned short* __restrict__ We2T, const float* __restrict__ be2,
    unsigned short* __restrict__ E, unsigned short* __restrict__ M) {
  __shared__ unsigned short Xt[64][136];   // 64 x 128 bf16, +8 pad
  __shared__ unsigned short Ht[64][136];   // 64 x 128 bf16 hidden chunk
  const int tid = threadIdx.x;
  const int wave = tid >> 6, lane = tid & 63, g = lane >> 4, r = lane & 15;
  const int row0 = blockIdx.x * 64;

  // stage gathered X tile, f32 -> bf16
#pragma unroll
  for (int p = 0; p < 8; ++p) {
    int e4 = (p * 256 + tid) * 4;
    int i = e4 >> 7, c = e4 & 127;
    int gi = row0 + i;
    const float* src;
    if (c < 64) src = self_obs + (size_t)(gi & (B_SZ - 1)) * 64 + c;
    else        src = obs + (size_t)(gi >> 4) * 1088 + 64 + (gi & 15) * 64 + (c - 64);
    float4 v = *(const float4*)src;
    ushort4 w;
    w.x = f2bf(v.x); w.y = f2bf(v.y); w.z = f2bf(v.z); w.w = f2bf(v.w);
    *(ushort4*)&Xt[i][c] = w;
  }
  __syncthreads();

  floatx4 eacc[4][4];  // [rt][ct]
#pragma unroll
  for (int a = 0; a < 4; ++a)
#pragma unroll
    for (int c2 = 0; c2 < 4; ++c2) eacc[a][c2] = (floatx4)0.0f;

  for (int chunk = 0; chunk < 4; ++chunk) {
    const int hbase = chunk * 128;
    floatx4 hacc[2][4];  // [ctl][rt]
#pragma unroll
    for (int a = 0; a < 2; ++a)
#pragma unroll
      for (int c2 = 0; c2 < 4; ++c2) hacc[a][c2] = (floatx4)0.0f;

#pragma unroll
    for (int kk = 0; kk < 4; ++kk) {   // K = 128
      short8v afr[4];
#pragma unroll
      for (int rt = 0; rt < 4; ++rt)
        afr[rt] = *(const short8v*)&Xt[rt * 16 + r][kk * 32 + g * 8];
#pragma unroll
      for (int ctl = 0; ctl < 2; ++ctl) {
        int col = hbase + wave * 32 + ctl * 16 + r;
        short8v bfr = *(const short8v*)&We1T[(size_t)col * 128 + kk * 32 + g * 8];
#pragma unroll
        for (int rt = 0; rt < 4; ++rt) hacc[ctl][rt] = MFMA(afr[rt], bfr, hacc[ctl][rt]);
      }
    }
    // bias + gelu(erf) -> Ht
#pragma unroll
    for (int ctl = 0; ctl < 2; ++ctl) {
      int col = hbase + wave * 32 + ctl * 16 + r;
      float bias = be1[col];
#pragma unroll
      for (int rt = 0; rt < 4; ++rt)
#pragma unroll
        for (int q = 0; q < 4; ++q) {
          float h = gelu_erf(hacc[ctl][rt][q] + bias);
          Ht[rt * 16 + g * 4 + q][wave * 32 + ctl * 16 + r] = f2bf(h);
        }
    }
    __syncthreads();
    // layer2 partial: E += gelu(H) @ We2[hbase:hbase+128, :]
#pragma unroll
    for (int kk = 0; kk < 4; ++kk) {
      short8v afr[4];
#pragma unroll
      for (int rt = 0; rt < 4; ++rt)
        afr[rt] = *(const short8v*)&Ht[rt * 16 + r][kk * 32 + g * 8];
#pragma unroll
      for (int ct = 0; ct < 4; ++ct) {
        int col = wave * 64 + ct * 16 + r;
        short8v bfr = *(const short8v*)&We2T[(size_t)col * 512 + hbase + kk * 32 + g * 8];
#pragma unroll
        for (int rt = 0; rt < 4; ++rt) eacc[rt][ct] = MFMA(afr[rt], bfr, eacc[rt][ct]);
      }
    }
    __syncthreads();
  }

  // epilogue: +bias, store E (bf16), 16-row group mean -> M
#pragma unroll
  for (int ct = 0; ct < 4; ++ct) {
    int col = wave * 64 + ct * 16 + r;
    float bias = be2[col];
#pragma unroll
    for (int rt = 0; rt < 4; ++rt) {
      float msum = 0.f;
#pragma unroll
      for (int q = 0; q < 4; ++q) {
        float e = eacc[rt][ct][q] + bias;
        int row = rt * 16 + g * 4 + q;
        E[(size_t)(row0 + row) * ED + col] = f2bf(e);
        msum += e;
      }
      msum += __shfl_xor(msum, 16);
      msum += __shfl_xor(msum, 32);
      if (g == 0) {
        int b = (row0 >> 4) + rt;
        M[(size_t)b * ED + col] = f2bf(msum * 0.0625f);
      }
    }
  }
}

// ---------------- K2: MV = M @ Wa1_bot + ba1  (8192 x 2048 x 256), bf16 out ------
// Tile 128x256, BK=64, 8 waves (2x4), wave 64x64. Same skeleton as k5a.
__global__ __launch_bounds__(512) void k2_mv(
    const unsigned short* __restrict__ M, const unsigned short* __restrict__ Wa1T,
    const float* __restrict__ ba1, unsigned short* __restrict__ MV) {
  __shared__ unsigned short Abuf[128 * 64];   // 16 KB
  __shared__ unsigned short Bbuf[256 * 64];   // 32 KB
  const int tid = threadIdx.x;
  const int wave = tid >> 6, lane = tid & 63, g = lane >> 4, r = lane & 15;
  const int wr = wave >> 2, wc = wave & 3;
  const int row0 = blockIdx.y * 128;
  const int col0 = blockIdx.x * 256;
  const int sr = lane >> 3, sc = lane & 7;
  const int swz = ((sc ^ sr) << 4);

  floatx4 acc[4][4];
#pragma unroll
  for (int a = 0; a < 4; ++a)
#pragma unroll
    for (int c2 = 0; c2 < 4; ++c2) acc[a][c2] = (floatx4)0.0f;

  for (int t = 0; t < 4; ++t) {
#pragma unroll
    for (int j = 0; j < 2; ++j) {
      int rowA = j * 64 + wave * 8 + sr;
      const char* src = (const char*)M + ((size_t)(row0 + rowA)) * 512 + t * 128 + swz;
      gll16(src, (char*)Abuf + (j * 512 + wave * 64) * 16);
    }
#pragma unroll
    for (int j = 0; j < 4; ++j) {
      int colB = j * 64 + wave * 8 + sr;
      // bottom half of Wa1T rows (k = 256..511 -> byte offset +512 of each 1KB col)
      const char* src = (const char*)Wa1T + ((size_t)(col0 + colB)) * 1024 + 512
                        + t * 128 + swz;
      gll16(src, (char*)Bbuf + (j * 512 + wave * 64) * 16);
    }
    __syncthreads();
#pragma unroll
    for (int kk = 0; kk < 2; ++kk) {
      const int off = (kk * 64 + g * 16) ^ ((r & 7) << 4);
      short8v afr[4], bfr[4];
#pragma unroll
      for (int rt = 0; rt < 4; ++rt)
        afr[rt] = *(const short8v*)((const char*)Abuf + (wr * 64 + rt * 16 + r) * 128 + off);
#pragma unroll
      for (int ct = 0; ct < 4; ++ct)
        bfr[ct] = *(const short8v*)((const char*)Bbuf + (wc * 64 + ct * 16 + r) * 128 + off);
#pragma unroll
      for (int rt = 0; rt < 4; ++rt)
#pragma unroll
        for (int ct = 0; ct < 4; ++ct) acc[rt][ct] = MFMA(afr[rt], bfr[ct], acc[rt][ct]);
    }
    __syncthreads();
  }

#pragma unroll
  for (int ct = 0; ct < 4; ++ct) {
    int col = col0 + wc * 64 + ct * 16 + r;
    float b1 = ba1[col];
#pragma unroll
    for (int rt = 0; rt < 4; ++rt)
#pragma unroll
      for (int q = 0; q < 4; ++q)
        MV[(size_t)(row0 + wr * 64 + rt * 16 + g * 4 + q) * 2048 + col] =
            f2bf(acc[rt][ct][q] + b1);
  }
}

// ---------------- K3: attention logits, 32-rows-per-wave + fragment-order Wa1 ----------
// Block = 8 waves (512 thr); wave w owns j0 = bid*16 + w*2 and j0+1; its 32 E-rows are
// i = r*8192 + j (nt=0,1). E fragments (32 rows x 256 k = 64 VGPR bf16) loaded ONCE ->
// E read exactly once globally. Each 1 KB Wa1 A-fragment read from LDS feeds 2 MFMAs
// (halves LDS-read traffic vs nt=1). Wa1F is pre-permuted to fragment order, so staging
// is a linear copy and every ds_read_b128 is a contiguous 1 KB -> zero bank conflicts.
// Loop over 2048 cols in 32-col chunks (64 chunks), double-buffered 2x16 KB LDS.
__global__ __launch_bounds__(512, 4) void k3_fused(
    const unsigned short* __restrict__ E, const unsigned short* __restrict__ MV,
    const unsigned short* __restrict__ Wa1F, const float* __restrict__ Wa2,
    float* __restrict__ L) {
  __shared__ char Bq[32768];   // 2 bufs x 16 frags x 1 KB
  const int tid = threadIdx.x;
  const int wave = tid >> 6, lane = tid & 63, g = lane >> 4, r = lane & 15;
  const int j0 = blockIdx.x * 16 + wave * 2;

  // ---- E preload: rows i = r*8192 + {j0, j0+1}, full K=256 ----
  short8v er0[8], er1[8];
  {
    const unsigned short* e0 = E + ((size_t)r * 8192 + j0) * 256 + g * 8;
    const unsigned short* e1 = e0 + 256;
#pragma unroll
    for (int kk = 0; kk < 8; ++kk) {
      er0[kk] = *(const short8v*)(e0 + kk * 32);
      er1[kk] = *(const short8v*)(e1 + kk * 32);
    }
  }

  // stage chunk c (16 frags = 16 KB): 2 linear gll16 per wave
  auto STAGE = [&](int c, int bufsel) {
#pragma unroll
    for (int cc = 0; cc < 2; ++cc) {
      const char* src = (const char*)Wa1F + (size_t)c * 16384
                        + (wave * 2 + cc) * 1024 + lane * 16;
      gll16(src, Bq + bufsel * 16384 + (wave * 2 + cc) * 1024);
    }
  };

  STAGE(0, 0);
  __syncthreads();

  float lgp0 = 0.f, lgp1 = 0.f;
  const unsigned short* mv0 = MV + (size_t)j0 * 2048;
  const unsigned short* mv1 = mv0 + 2048;

  for (int c = 0; c < 64; ++c) {
    if (c + 1 < 64) STAGE(c + 1, (c + 1) & 1);
    // per-chunk constants: mv (bf16, per j x col) and Wa2 (per col); uniform over r
    ushort4 mq0[2], mq1[2];
    float4 w2[2];
#pragma unroll
    for (int ct = 0; ct < 2; ++ct) {
      mq0[ct] = *(const ushort4*)(mv0 + c * 32 + ct * 16 + g * 4);
      mq1[ct] = *(const ushort4*)(mv1 + c * 32 + ct * 16 + g * 4);
      w2[ct] = *(const float4*)&Wa2[c * 32 + ct * 16 + g * 4];
    }
    floatx4 acc0[2], acc1[2];
    acc0[0] = (floatx4)0.0f; acc0[1] = (floatx4)0.0f;
    acc1[0] = (floatx4)0.0f; acc1[1] = (floatx4)0.0f;
    const char* bufb = Bq + (c & 1) * 16384;
#pragma unroll
    for (int kk = 0; kk < 8; ++kk) {
#pragma unroll
      for (int ct = 0; ct < 2; ++ct) {
        short8v a = *(const short8v*)(bufb + (ct * 8 + kk) * 1024 + lane * 16);
        acc0[ct] = MFMA(a, er0[kk], acc0[ct]);
        acc1[ct] = MFMA(a, er1[kk], acc1[ct]);
      }
    }
    // chunk epilogue: h = acc + mv; lg += gelu(h) . Wa2  (no shuffles)
#pragma unroll
    for (int ct = 0; ct < 2; ++ct) {
      const float* wp = (const float*)&w2[ct];
      const unsigned short* m0p = (const unsigned short*)&mq0[ct];
      const unsigned short* m1p = (const unsigned short*)&mq1[ct];
#pragma unroll
      for (int q = 0; q < 4; ++q) {
        lgp0 = fmaf(gelu_poly(acc0[ct][q] + bf2f(m0p[q])), wp[q], lgp0);
        lgp1 = fmaf(gelu_poly(acc1[ct][q] + bf2f(m1p[q])), wp[q], lgp1);
      }
    }
    __syncthreads();   // stage(c+1) drained; also fences buf reads
  }

  // reduce across the 4 g-groups (disjoint col subsets), write logits
  lgp0 += __shfl_xor(lgp0, 16); lgp0 += __shfl_xor(lgp0, 32);
  lgp1 += __shfl_xor(lgp1, 16); lgp1 += __shfl_xor(lgp1, 32);
  if (g == 0) {
    L[(size_t)r * 8192 + j0] = lgp0;
    L[(size_t)r * 8192 + j0 + 1] = lgp1;
  }
}

// ---------------- K4: softmax over 16 neighbors (consecutive rows) ----------------
__global__ __launch_bounds__(256) void k4_softmax(
    const float* __restrict__ L, const float* __restrict__ ba2,
    float* __restrict__ attnw) {
  int row = blockIdx.x * 256 + threadIdx.x;
  float logit = L[row] + ba2[0];
  float m = logit;
  m = fmaxf(m, __shfl_xor(m, 1)); m = fmaxf(m, __shfl_xor(m, 2));
  m = fmaxf(m, __shfl_xor(m, 4)); m = fmaxf(m, __shfl_xor(m, 8));
  float e = expf(logit - m);
  float s = e;
  s += __shfl_xor(s, 1); s += __shfl_xor(s, 2);
  s += __shfl_xor(s, 4); s += __shfl_xor(s, 8);
  attnw[row] = e / s;
}

// ---------------- K5a: gelu(E @ Wv1 + bv1) weighted by attn, 16-row reduce -> G ----------
// M=131072, N=1024, K=256. Tile 128x256, BK=64, 8 waves (2x4), wave 64x64.
// Epilogue: G[b] = sum over 16 consecutive rows of attn[i]*gelu(h).  G bf16 (8192x1024).
__global__ __launch_bounds__(512) void k5a_gemm(
    const unsigned short* __restrict__ E, const unsigned short* __restrict__ Wv1T,
    const float* __restrict__ bv1, const float* __restrict__ attnw,
    unsigned short* __restrict__ G) {
  __shared__ unsigned short Abuf[128 * 64];   // 16 KB
  __shared__ unsigned short Bbuf[256 * 64];   // 32 KB
  const int tid = threadIdx.x;
  const int wave = tid >> 6, lane = tid & 63, g = lane >> 4, r = lane & 15;
  const int wr = wave >> 2, wc = wave & 3;
  const int nb = blockIdx.x;                  // 0..3
  const int row0 = blockIdx.y * 128;
  const int col0 = nb * 256;
  const int sr = lane >> 3, sc = lane & 7;
  const int swz = ((sc ^ sr) << 4);

  floatx4 acc[4][4];
#pragma unroll
  for (int a = 0; a < 4; ++a)
#pragma unroll
    for (int c2 = 0; c2 < 4; ++c2) acc[a][c2] = (floatx4)0.0f;

  for (int t = 0; t < 4; ++t) {
#pragma unroll
    for (int j = 0; j < 2; ++j) {
      int rowA = j * 64 + wave * 8 + sr;
      const char* src = (const char*)E + ((size_t)(row0 + rowA)) * 512 + t * 128 + swz;
      gll16(src, (char*)Abuf + (j * 512 + wave * 64) * 16);
    }
#pragma unroll
    for (int j = 0; j < 4; ++j) {
      int colB = j * 64 + wave * 8 + sr;
      const char* src = (const char*)Wv1T + ((size_t)(col0 + colB)) * 512 + t * 128 + swz;
      gll16(src, (char*)Bbuf + (j * 512 + wave * 64) * 16);
    }
    __syncthreads();
#pragma unroll
    for (int kk = 0; kk < 2; ++kk) {
      const int off = (kk * 64 + g * 16) ^ ((r & 7) << 4);
      short8v afr[4], bfr[4];
#pragma unroll
      for (int rt = 0; rt < 4; ++rt)
        afr[rt] = *(const short8v*)((const char*)Abuf + (wr * 64 + rt * 16 + r) * 128 + off);
#pragma unroll
      for (int ct = 0; ct < 4; ++ct)
        bfr[ct] = *(const short8v*)((const char*)Bbuf + (wc * 64 + ct * 16 + r) * 128 + off);
#pragma unroll
      for (int rt = 0; rt < 4; ++rt)
#pragma unroll
        for (int ct = 0; ct < 4; ++ct) acc[rt][ct] = MFMA(afr[rt], bfr[ct], acc[rt][ct]);
    }
    __syncthreads();
  }

  // ---- epilogue: weighted gelu + 16-row reduce -> G ----
  float aw[4][4];
#pragma unroll
  for (int rt = 0; rt < 4; ++rt)
#pragma unroll
    for (int q = 0; q < 4; ++q)
      aw[rt][q] = attnw[row0 + wr * 64 + rt * 16 + g * 4 + q];
#pragma unroll
  for (int ct = 0; ct < 4; ++ct) {
    int col = col0 + wc * 64 + ct * 16 + r;
    float b1 = bv1[col];
#pragma unroll
    for (int rt = 0; rt < 4; ++rt) {
      float s = 0.f;
#pragma unroll
      for (int q = 0; q < 4; ++q)
        s = fmaf(aw[rt][q], gelu_poly(acc[rt][ct][q] + b1), s);
      s += __shfl_xor(s, 16);
      s += __shfl_xor(s, 32);
      if (g == 0)
        G[(size_t)((row0 >> 4) + wr * 4 + rt) * 1024 + col] = f2bf(s);
    }
  }
}

// ---------------- K5b: out = G @ Wv2 + bv2  (8192 x 1024 x 256) ----------------
// Tile 64x128, BK=64, 4 waves (2x2), wave 32x64.
__global__ __launch_bounds__(256) void k5b_gemm(
    const unsigned short* __restrict__ G, const unsigned short* __restrict__ Wv2T,
    const float* __restrict__ bv2, float* __restrict__ out) {
  __shared__ unsigned short Abuf[64 * 64];    // 8 KB
  __shared__ unsigned short Bbuf[128 * 64];   // 16 KB
  const int tid = threadIdx.x;
  const int wave = tid >> 6, lane = tid & 63, g = lane >> 4, r = lane & 15;
  const int wr = wave >> 1, wc = wave & 1;
  const int col0 = blockIdx.x * 128;
  const int row0 = blockIdx.y * 64;
  const int sr = lane >> 3, sc = lane & 7;
  const int swz = ((sc ^ sr) << 4);

  floatx4 acc[2][4];
#pragma unroll
  for (int a = 0; a < 2; ++a)
#pragma unroll
    for (int c2 = 0; c2 < 4; ++c2) acc[a][c2] = (floatx4)0.0f;

  for (int t = 0; t < 16; ++t) {
#pragma unroll
    for (int j = 0; j < 2; ++j) {
      int rowA = j * 32 + wave * 8 + sr;
      const char* src = (const char*)G + ((size_t)(row0 + rowA)) * 2048 + t * 128 + swz;
      gll16(src, (char*)Abuf + (j * 256 + wave * 64) * 16);
    }
#pragma unroll
    for (int j = 0; j < 4; ++j) {
      int colB = j * 32 + wave * 8 + sr;
      const char* src = (const char*)Wv2T + ((size_t)(col0 + colB)) * 2048 + t * 128 + swz;
      gll16(src, (char*)Bbuf + (j * 256 + wave * 64) * 16);
    }
    __syncthreads();
#pragma unroll
    for (int kk = 0; kk < 2; ++kk) {
      const int off = (kk * 64 + g * 16) ^ ((r & 7) << 4);
      short8v afr[2], bfr[4];
#pragma unroll
      for (int rt = 0; rt < 2; ++rt)
        afr[rt] = *(const short8v*)((const char*)Abuf + (wr * 32 + rt * 16 + r) * 128 + off);
#pragma unroll
      for (int ct = 0; ct < 4; ++ct)
        bfr[ct] = *(const short8v*)((const char*)Bbuf + (wc * 64 + ct * 16 + r) * 128 + off);
#pragma unroll
      for (int rt = 0; rt < 2; ++rt)
#pragma unroll
        for (int ct = 0; ct < 4; ++ct) acc[rt][ct] = MFMA(afr[rt], bfr[ct], acc[rt][ct]);
    }
    __syncthreads();
  }

#pragma unroll
  for (int ct = 0; ct < 4; ++ct) {
    int col = col0 + wc * 64 + ct * 16 + r;
    float b = bv2[col];
#pragma unroll
    for (int rt = 0; rt < 2; ++rt)
#pragma unroll
      for (int q = 0; q < 4; ++q)
        out[(size_t)(row0 + wr * 32 + rt * 16 + g * 4 + q) * ED + col] =
            acc[rt][ct][q] + b;
  }
}

extern "C" void kernel_launch(void* const* d_in, const int* in_sizes, int n_in,
                              void* d_out, int out_size, void* d_ws, size_t ws_size,
                              hipStream_t stream) {
  const float* self_obs = (const float*)d_in[0];
  const float* obs = (const float*)d_in[1];
  const float* We1 = (const float*)d_in[2];
  const float* be1 = (const float*)d_in[3];
  const float* We2 = (const float*)d_in[4];
  const float* be2 = (const float*)d_in[5];
  const float* Wv1 = (const float*)d_in[6];
  const float* bv1 = (const float*)d_in[7];
  const float* Wv2 = (const float*)d_in[8];
  const float* bv2 = (const float*)d_in[9];
  const float* Wa1 = (const float*)d_in[10];
  const float* ba1 = (const float*)d_in[11];
  const float* Wa2 = (const float*)d_in[12];
  const float* ba2 = (const float*)d_in[13];
  float* out = (float*)d_out;

  char* ws = (char*)d_ws;
  size_t off = 0;
  auto alloc = [&](size_t bytes) {
    char* p = ws + off;
    off += (bytes + 255) & ~(size_t)255;
    return p;
  };
  unsigned short* E    = (unsigned short*)alloc((size_t)BK * ED * 2);      // 64 MB
  unsigned short* M    = (unsigned short*)alloc((size_t)B_SZ * ED * 2);    // 4 MB
  float*          attn = (float*)alloc((size_t)BK * 4);                    // 0.5 MB
  unsigned short* MV   = (unsigned short*)alloc((size_t)B_SZ * 2048 * 2);  // 32 MB
  float*          L    = (float*)alloc((size_t)BK * 4);                    // 0.5 MB
  unsigned short* We1T = (unsigned short*)alloc(128 * 512 * 2);
  unsigned short* We2T = (unsigned short*)alloc(512 * 256 * 2);
  unsigned short* Wv1T = (unsigned short*)alloc(256 * 1024 * 2);
  unsigned short* Wv2T = (unsigned short*)alloc(1024 * 256 * 2);
  unsigned short* Wa1T = (unsigned short*)alloc(512 * 2048 * 2);
  unsigned short* Wa1F = (unsigned short*)alloc(2048 * 256 * 2);           // 1 MB
  // G (8192x1024 bf16, 16 MB) aliases MV (32 MB, dead after k3)
  unsigned short* G    = (unsigned short*)MV;

  wt_kernel<<<(128 * 512 + 255) / 256, 256, 0, stream>>>(We1, We1T, 128, 512);
  wt_kernel<<<(512 * 256 + 255) / 256, 256, 0, stream>>>(We2, We2T, 512, 256);
  wt_kernel<<<(256 * 1024 + 255) / 256, 256, 0, stream>>>(Wv1, Wv1T, 256, 1024);
  wt_kernel<<<(1024 * 256 + 255) / 256, 256, 0, stream>>>(Wv2, Wv2T, 1024, 256);
  wt_kernel<<<(512 * 2048 + 255) / 256, 256, 0, stream>>>(Wa1, Wa1T, 512, 2048);
  wa1f_kernel<<<2048, 256, 0, stream>>>(Wa1, Wa1F);

  k1_kernel<<<BK / 64, 256, 0, stream>>>(self_obs, obs, We1T, be1, We2T, be2, E, M);
  k2_mv<<<dim3(8, 64), 512, 0, stream>>>(M, Wa1T, ba1, MV);
  k3_fused<<<B_SZ / 16, 512, 0, stream>>>(E, MV, Wa1F, Wa2, L);
  k4_softmax<<<BK / 256, 256, 0, stream>>>(L, ba2, attn);
  k5a_gemm<<<dim3(4, 1024), 512, 0, stream>>>(E, Wv1T, bv1, attn, G);
  k5b_gemm<<<dim3(2, 128), 256, 0, stream>>>(G, Wv2T, bv2, out);
}